// Round 12
// baseline (425.161 us; speedup 1.0000x reference)
//
#include <hip/hip_runtime.h>
#include <hip/hip_bf16.h>
#include <stdint.h>
#include <math.h>

#define CH 256

typedef __attribute__((ext_vector_type(8)))  short short8;
typedef __attribute__((ext_vector_type(16))) short short16;
typedef __attribute__((ext_vector_type(4)))  float f32x4;

#define GL2LDS16(g, l) __builtin_amdgcn_global_load_lds(                       \
    (const __attribute__((address_space(1))) void*)(g),                        \
    (__attribute__((address_space(3))) void*)(l), 16, 0, 0)

__device__ inline short f2bf(float f) {
    __hip_bfloat16 h = __float2bfloat16(f);
    short s;
    __builtin_memcpy(&s, &h, 2);
    return s;
}

__device__ inline float bf2f(short s) {
    unsigned u = ((unsigned)(unsigned short)s) << 16;
    float f;
    __builtin_memcpy(&f, &u, 4);
    return f;
}

__device__ inline float warp_sum64(float v) {
    v += __shfl_xor(v, 32, 64);
    v += __shfl_xor(v, 16, 64);
    v += __shfl_xor(v, 8, 64);
    v += __shfl_xor(v, 4, 64);
    v += __shfl_xor(v, 2, 64);
    v += __shfl_xor(v, 1, 64);
    return v;
}

__device__ inline float warp_max64(float v) {
    v = fmaxf(v, __shfl_xor(v, 32, 64));
    v = fmaxf(v, __shfl_xor(v, 16, 64));
    v = fmaxf(v, __shfl_xor(v, 8, 64));
    v = fmaxf(v, __shfl_xor(v, 4, 64));
    v = fmaxf(v, __shfl_xor(v, 2, 64));
    v = fmaxf(v, __shfl_xor(v, 1, 64));
    return v;
}

// ==================================================================== MFMA GEMM
// BMxBN tile, BK=64, 2x2 wave grid, 16x16x32 bf16 MFMA. Single-buffer
// 2-barrier K-loop. (R19 config: Q rides GEMM1's DUAL; scan fold; XSWZ.)
// R20: GEMM2+GEMM3 merged into chain_gemm (ticket roles + spin gate) — this
//      template keeps the remaining call sites.
struct GArgs {
    const short* A; const short* Bt; const float* bias; const float* res;
    float* C; short* Cbf;
    const float* gamma; const float* beta; float* vbar;
    int M, K, Nc, ldc, coff;
    const short* A2; const short* Bt2; const float* bias2; short* Cbf2;
    int M2, Nc2, y_split, K2;
    const int* coli;
    int* cursor; int* elist;
    const int* counts; int* offsets; int Nn;   // SCAN role
};

template <int BM, int BN, int EPI, int DUAL, int VB, int FILL,
          int SCAN = 0, int PAN2 = 0, int XSWZ = 0>
__global__ __launch_bounds__(256) void mfma_gemm(GArgs g)
{
    constexpr int BK = 64;
    constexpr int HM = BM / 2, HN = BN / 2;
    constexpr int FM = HM / 16, FN = HN / 16;
    constexpr int PA = BM / 32;
    constexpr int PB = BN / 32;
    constexpr int NP2 = PAN2 ? 2 : 1;
    __shared__ short As[BM * BK];
    __shared__ short Bs[NP2 * BN * BK];

    const short* A = g.A; const short* Bt = g.Bt;
    const float* bias = g.bias; const float* res = g.res;
    float* C = g.C; short* Cbf = g.Cbf;
    int M = g.M, ldc = g.ldc, co = g.coff;
    int K = g.K;
    int by = blockIdx.y, bx = blockIdx.x;

    if constexpr (SCAN) {
        if (by == (int)gridDim.y - 1) {
            const int t0 = threadIdx.x;
            if (bx == 0) {
                int* ss = (int*)As;
                int base8 = t0 * 8;
                int loc[8]; int srun = 0;
                #pragma unroll
                for (int j = 0; j < 8; j++) {
                    int idx = base8 + j;
                    int c = (idx < g.Nn) ? g.counts[idx] : 0;
                    loc[j] = srun; srun += c;
                }
                ss[t0] = srun;
                __syncthreads();
                for (int off = 1; off < 256; off <<= 1) {
                    int v = (t0 >= off) ? ss[t0 - off] : 0;
                    __syncthreads();
                    ss[t0] += v;
                    __syncthreads();
                }
                int excl = (t0 > 0) ? ss[t0 - 1] : 0;
                #pragma unroll
                for (int j = 0; j < 8; j++) {
                    int idx = base8 + j;
                    if (idx < g.Nn) {
                        int v = excl + loc[j];
                        g.offsets[idx] = v;
                        g.cursor[idx]  = v;
                    }
                }
                if (t0 == 255) g.offsets[g.Nn] = ss[255];
            }
            return;
        }
    }

    bool qrole = false;
    if constexpr (DUAL) {
        if (by >= g.y_split) {
            by -= g.y_split;
            if (bx * BN >= g.Nc2) return;
            qrole = true;
            A = g.A2; Bt = g.Bt2; bias = g.bias2; Cbf = g.Cbf2;
            C = nullptr; res = nullptr;
            M = g.M2; ldc = g.Nc2; co = 0; K = g.K2;
        }
    }

    if constexpr (XSWZ) {
        if (!qrole) {
            int h = by * 4 + bx;               // gridDim.x == 4
            int lby = (h >> 5) * 8 + (h & 7);  // same-XCD ids share lby
            if (lby * BM >= M) return;         // guard padded rows
            by = lby;
            bx = (h >> 3) & 3;
        }
    }

    const int t = threadIdx.x;
    const int wave = t >> 6, lane = t & 63;
    const int q = lane >> 4, l16 = lane & 15;
    const int row0 = by * BM;
    const int col0 = bx * BN;
    const int wm = wave & 1, wn = wave >> 1;

    if constexpr (FILL) {
        if (!qrole && bx == 0 && t < BM) {
            int rg = row0 + t;
            if (rg < M) {
                int c = g.coli[rg];
                int p = atomicAdd(&g.cursor[c], 1);
                g.elist[p] = rg;
            }
        }
    }

    f32x4 acc[NP2][FM][FN];
    #pragma unroll
    for (int p2 = 0; p2 < NP2; p2++)
        #pragma unroll
        for (int i = 0; i < FM; i++)
            #pragma unroll
            for (int j = 0; j < FN; j++) acc[p2][i][j] = (f32x4){0.f, 0.f, 0.f, 0.f};

    for (int k0 = 0; k0 < K; k0 += BK) {
        #pragma unroll
        for (int p = 0; p < PA; p++) {
            int chunk = p * 256 + t;
            int r = chunk >> 3;
            int cs = (((chunk & 7) ^ (r & 7)) * 8);   // XOR bank swizzle
            int gr = row0 + r; if (gr >= M) gr = M - 1;
            const short* gsrc = A + (size_t)gr * K + k0 + cs;
            short* ldst = &As[(p * 256 + wave * 64) * 8];
            GL2LDS16(gsrc, ldst);
        }
        #pragma unroll
        for (int p2 = 0; p2 < NP2; p2++) {
            if (!(PAN2 && p2 == 1 && qrole)) {
                #pragma unroll
                for (int p = 0; p < PB; p++) {
                    int chunk = p * 256 + t;
                    int r = chunk >> 3;
                    int cs = (((chunk & 7) ^ (r & 7)) * 8);
                    const short* gsrc = Bt + (size_t)(col0 + p2 * 256 + r) * K + k0 + cs;
                    short* ldst = &Bs[p2 * BN * BK + (p * 256 + wave * 64) * 8];
                    GL2LDS16(gsrc, ldst);
                }
            }
        }
        __syncthreads();
        #pragma unroll
        for (int ks = 0; ks < 2; ks++) {
            short8 af[FM];
            #pragma unroll
            for (int mi = 0; mi < FM; mi++) {
                int R = wm * HM + mi * 16 + l16;
                int slot = ((ks * 4 + q) ^ (R & 7)) * 8;
                af[mi] = *(const short8*)&As[R * BK + slot];
            }
            #pragma unroll
            for (int p2 = 0; p2 < NP2; p2++) {
                if (!(PAN2 && p2 == 1 && qrole)) {
                    short8 bfr[FN];
                    #pragma unroll
                    for (int ni = 0; ni < FN; ni++) {
                        int R = wn * HN + ni * 16 + l16;
                        int slot = ((ks * 4 + q) ^ (R & 7)) * 8;
                        bfr[ni] = *(const short8*)&Bs[p2 * BN * BK + R * BK + slot];
                    }
                    #pragma unroll
                    for (int mi = 0; mi < FM; mi++)
                        #pragma unroll
                        for (int ni = 0; ni < FN; ni++)
                            acc[p2][mi][ni] = __builtin_amdgcn_mfma_f32_16x16x32_bf16(
                                af[mi], bfr[ni], acc[p2][mi][ni], 0, 0, 0);
                }
            }
        }
        __syncthreads();
    }

    // ---- epilogue; C/D layout: col = l16, row = q*4 + r ----
    #pragma unroll
    for (int p2 = 0; p2 < NP2; p2++) {
        if (PAN2 && p2 == 1 && qrole) continue;
        #pragma unroll
        for (int ni = 0; ni < FN; ni++) {
            int cg = col0 + p2 * 256 + wn * HN + ni * 16 + l16;
            float bv = bias[cg];
            if (EPI == 1 && !qrole) {
                float ga = g.gamma[cg], be = g.beta[cg];
                #pragma unroll
                for (int mi = 0; mi < FM; mi++) {
                    #pragma unroll
                    for (int r = 0; r < 4; r++) {
                        float v = acc[p2][mi][ni][r] + bv;
                        float s = v, sq = v * v;
                        s += __shfl_xor(s, 1, 64);  sq += __shfl_xor(sq, 1, 64);
                        s += __shfl_xor(s, 2, 64);  sq += __shfl_xor(sq, 2, 64);
                        s += __shfl_xor(s, 4, 64);  sq += __shfl_xor(sq, 4, 64);
                        float mean = s * 0.125f;
                        float var = sq * 0.125f - mean * mean;
                        float o = fmaxf((v - mean) * rsqrtf(var + 1e-5f) * ga + be, 0.f);
                        int rg = row0 + wm * HM + mi * 16 + q * 4 + r;
                        if (rg < M) Cbf[(size_t)rg * ldc + co + cg] = f2bf(o);
                    }
                }
            } else {
                #pragma unroll
                for (int mi = 0; mi < FM; mi++) {
                    #pragma unroll
                    for (int r = 0; r < 4; r++) {
                        int rg = row0 + wm * HM + mi * 16 + q * 4 + r;
                        if (rg < M) {
                            float v = acc[p2][mi][ni][r] + bv;
                            if (res) v += res[(size_t)rg * ldc + co + cg];
                            if (C)   C[(size_t)rg * ldc + co + cg] = v;
                            if (Cbf) Cbf[(size_t)rg * ldc + co + cg] = f2bf(v);
                        }
                    }
                }
                if constexpr (VB) {
                    bool vpanel = PAN2 ? (p2 == 1) : (!qrole && cg >= 256);
                    if (vpanel && !qrole) {
                        float part = 0.f;
                        #pragma unroll
                        for (int mi = 0; mi < FM; mi++)
                            #pragma unroll
                            for (int r = 0; r < 4; r++) {
                                int rg = row0 + wm * HM + mi * 16 + q * 4 + r;
                                if (rg < M) part += acc[p2][mi][ni][r] + bv;
                            }
                        part += __shfl_xor(part, 16, 64);
                        part += __shfl_xor(part, 32, 64);
                        if (q == 0) atomicAdd(&g.vbar[cg - 256], part);
                    }
                }
            }
        }
    }
}

// ==================================================================== chain GEMM
// R20: GEMM2 (eout/eo_bf, 1024 tiles) + GEMM3 (KV 2-panel, 1024 tiles) in ONE
// launch. Roles via global ticket: first 1024 arrivals produce (deadlock-safe
// under ANY dispatch order — any resident block produces while work remains).
// Producers release their row panel (threadfence + done[panel]++); consumers
// acquire-spin until done[panel]==4. XSWZ keeps panel p's producer/consumer
// on the same XCD -> L2-local handoff. Overlaps GEMM3 ramp with GEMM2 drain.
struct ChainArgs {
    const short* A1; const short* Bt1; const float* bias1; const float* res1;
    float* C1; short* Cbf1;
    const short* A2; const short* Bt2; const float* bias2; short* Cbf2;
    float* vbar;
    const int* coli; int* cursor; int* elist;
    int M;
    int* ticket; int* done;
};

__global__ __launch_bounds__(256) void chain_gemm(ChainArgs g)
{
    constexpr int BK = 64;
    __shared__ short As[64 * BK];
    __shared__ short Bs[2 * 64 * BK];
    __shared__ int stick;
    const int t = threadIdx.x;
    if (t == 0) stick = atomicAdd(g.ticket, 1);
    __syncthreads();
    const int tick = stick;
    const bool crole = tick >= 1024;
    int h = crole ? tick - 1024 : tick;
    int by = (h >> 5) * 8 + (h & 7);   // XSWZ: same-XCD ids share panel
    int bx = (h >> 3) & 3;
    const int M = g.M;
    if (by * 64 >= M) return;          // padded panels (250..255): no-op both roles

    const int wave = t >> 6, lane = t & 63;
    const int q = lane >> 4, l16 = lane & 15;
    const int row0 = by * 64;
    const int col0 = bx * 64;
    const int wm = wave & 1, wn = wave >> 1;
    const int NP2 = crole ? 2 : 1;

    const short* A    = crole ? g.A2    : g.A1;
    const short* Bt   = crole ? g.Bt2   : g.Bt1;
    const float* bias = crole ? g.bias2 : g.bias1;

    if (crole && bx == 0 && t < 64) {   // CSR fill (indep of eo data)
        int rg = row0 + t;
        if (rg < M) {
            int c = g.coli[rg];
            int p = atomicAdd(&g.cursor[c], 1);
            g.elist[p] = rg;
        }
    }

    if (crole) {                        // gate on producer panel completion
        if (t == 0) {
            while (__hip_atomic_load(g.done + by, __ATOMIC_ACQUIRE,
                                     __HIP_MEMORY_SCOPE_AGENT) < 4)
                __builtin_amdgcn_s_sleep(8);
        }
        __syncthreads();
    }

    f32x4 acc[2][2][2];
    #pragma unroll
    for (int p2 = 0; p2 < 2; p2++)
        #pragma unroll
        for (int i = 0; i < 2; i++)
            #pragma unroll
            for (int j = 0; j < 2; j++) acc[p2][i][j] = (f32x4){0.f, 0.f, 0.f, 0.f};

    for (int k0 = 0; k0 < 256; k0 += BK) {
        #pragma unroll
        for (int p = 0; p < 2; p++) {
            int chunk = p * 256 + t;
            int r = chunk >> 3;
            int cs = (((chunk & 7) ^ (r & 7)) * 8);
            int gr = row0 + r; if (gr >= M) gr = M - 1;
            const short* gsrc = A + (size_t)gr * 256 + k0 + cs;
            short* ldst = &As[(p * 256 + wave * 64) * 8];
            GL2LDS16(gsrc, ldst);
        }
        for (int p2 = 0; p2 < NP2; p2++) {
            #pragma unroll
            for (int p = 0; p < 2; p++) {
                int chunk = p * 256 + t;
                int r = chunk >> 3;
                int cs = (((chunk & 7) ^ (r & 7)) * 8);
                const short* gsrc = Bt + (size_t)(col0 + p2 * 256 + r) * 256 + k0 + cs;
                short* ldst = &Bs[p2 * 64 * BK + (p * 256 + wave * 64) * 8];
                GL2LDS16(gsrc, ldst);
            }
        }
        __syncthreads();
        #pragma unroll
        for (int ks = 0; ks < 2; ks++) {
            short8 af[2];
            #pragma unroll
            for (int mi = 0; mi < 2; mi++) {
                int R = wm * 32 + mi * 16 + l16;
                int slot = ((ks * 4 + q) ^ (R & 7)) * 8;
                af[mi] = *(const short8*)&As[R * BK + slot];
            }
            for (int p2 = 0; p2 < NP2; p2++) {
                short8 bfr[2];
                #pragma unroll
                for (int ni = 0; ni < 2; ni++) {
                    int R = wn * 32 + ni * 16 + l16;
                    int slot = ((ks * 4 + q) ^ (R & 7)) * 8;
                    bfr[ni] = *(const short8*)&Bs[p2 * 64 * BK + R * BK + slot];
                }
                #pragma unroll
                for (int mi = 0; mi < 2; mi++)
                    #pragma unroll
                    for (int ni = 0; ni < 2; ni++)
                        acc[p2][mi][ni] = __builtin_amdgcn_mfma_f32_16x16x32_bf16(
                            af[mi], bfr[ni], acc[p2][mi][ni], 0, 0, 0);
            }
        }
        __syncthreads();
    }

    if (!crole) {
        // ---- producer epilogue: eout (f32, +eattr) + eo_bf ----
        #pragma unroll
        for (int ni = 0; ni < 2; ni++) {
            int cg = col0 + wn * 32 + ni * 16 + l16;
            float bv = g.bias1[cg];
            #pragma unroll
            for (int mi = 0; mi < 2; mi++) {
                #pragma unroll
                for (int r = 0; r < 4; r++) {
                    int rg = row0 + wm * 32 + mi * 16 + q * 4 + r;
                    if (rg < M) {
                        float v = acc[0][mi][ni][r] + bv
                                + g.res1[(size_t)rg * 256 + cg];
                        g.C1[(size_t)rg * 256 + cg] = v;
                        g.Cbf1[(size_t)rg * 256 + cg] = f2bf(v);
                    }
                }
            }
        }
        __threadfence();                 // release panel (agent scope)
        __syncthreads();
        if (t == 0) atomicAdd(g.done + by, 1);
    } else {
        // ---- consumer epilogue: kv_bf (2 panels) + vbar ----
        #pragma unroll
        for (int p2 = 0; p2 < 2; p2++) {
            #pragma unroll
            for (int ni = 0; ni < 2; ni++) {
                int cg = col0 + p2 * 256 + wn * 32 + ni * 16 + l16;
                float bv = g.bias2[cg];
                #pragma unroll
                for (int mi = 0; mi < 2; mi++) {
                    #pragma unroll
                    for (int r = 0; r < 4; r++) {
                        int rg = row0 + wm * 32 + mi * 16 + q * 4 + r;
                        if (rg < M)
                            g.Cbf2[(size_t)rg * 512 + cg] =
                                f2bf(acc[p2][mi][ni][r] + bv);
                    }
                }
                if (p2 == 1) {
                    float part = 0.f;
                    #pragma unroll
                    for (int mi = 0; mi < 2; mi++)
                        #pragma unroll
                        for (int r = 0; r < 4; r++) {
                            int rg = row0 + wm * 32 + mi * 16 + q * 4 + r;
                            if (rg < M) part += acc[p2][mi][ni][r] + bv;
                        }
                    part += __shfl_xor(part, 16, 64);
                    part += __shfl_xor(part, 32, 64);
                    if (q == 0) atomicAdd(&g.vbar[cg - 256], part);
                }
            }
        }
    }
}

// ==================================================================== merged prep
struct PrepPack {
    const float* wsrc[8];
    short* wdst[8];
    int wK[8];
    int wstart[8];
    int NW, NP;
    const float* x;
    short* x_bf;
    short* cat_bf;
    float2* xs;
    const float* gng;
    const float* gnb;
    float* vbar;
    const float* bk;
    const float* bv;
    float* bkv;
    int* counts;
    int* doneZ; int* ticketZ;
    int N;
};

__global__ __launch_bounds__(256) void prep_kernel(PrepPack p)
{
    int bid = blockIdx.x;
    int t = threadIdx.x;
    if (bid < p.NW) {
        int m = 0;
        #pragma unroll
        for (int i = 1; i < 8; i++) if (bid >= p.wstart[i]) m = i;
        int k0 = (bid - p.wstart[m]) * 16;
        const float* src = p.wsrc[m];
        short16 o;
        #pragma unroll
        for (int j = 0; j < 16; j++) o[j] = f2bf(src[(size_t)(k0 + j) * 256 + t]);
        *(short16*)(p.wdst[m] + (size_t)t * p.wK[m] + k0) = o;
        return;
    }
    if (bid >= p.NW + p.NP) {
        int i = (bid - p.NW - p.NP) * 256 + t;
        if (i < p.N) p.counts[i] = 0;
        return;
    }
    int pb = bid - p.NW;
    if (pb == 0) {
        p.vbar[t] = 0.f;
        p.bkv[t] = p.bk[t];
        p.bkv[256 + t] = p.bv[t];
        p.doneZ[t] = 0;
        if (t == 0) p.ticketZ[0] = 0;
    }
    int r = pb * 8 + (t >> 5);
    int g = t & 31;
    if (r >= p.N) return;
    size_t xb = (size_t)r * CH + g * 8;
    float4 a = *(const float4*)&p.x[xb];
    float4 b = *(const float4*)&p.x[xb + 4];
    short8 xr;
    xr[0] = f2bf(a.x); xr[1] = f2bf(a.y); xr[2] = f2bf(a.z); xr[3] = f2bf(a.w);
    xr[4] = f2bf(b.x); xr[5] = f2bf(b.y); xr[6] = f2bf(b.z); xr[7] = f2bf(b.w);
    *(short8*)&p.x_bf[xb] = xr;
    float s  = a.x + a.y + a.z + a.w + b.x + b.y + b.z + b.w;
    float s2 = a.x*a.x + a.y*a.y + a.z*a.z + a.w*a.w
             + b.x*b.x + b.y*b.y + b.z*b.z + b.w*b.w;
    p.xs[(size_t)r * 32 + g] = make_float2(s, s2);
    float m = s * 0.125f;
    float var = s2 * 0.125f - m * m;
    float rsd = rsqrtf(var + 1e-5f);
    float4 g0 = *(const float4*)&p.gng[g * 8];
    float4 g1 = *(const float4*)&p.gng[g * 8 + 4];
    float4 b0 = *(const float4*)&p.gnb[g * 8];
    float4 b1 = *(const float4*)&p.gnb[g * 8 + 4];
    short8 o;
    o[0] = f2bf(fmaxf((a.x - m) * rsd * g0.x + b0.x, 0.f));
    o[1] = f2bf(fmaxf((a.y - m) * rsd * g0.y + b0.y, 0.f));
    o[2] = f2bf(fmaxf((a.z - m) * rsd * g0.z + b0.z, 0.f));
    o[3] = f2bf(fmaxf((a.w - m) * rsd * g0.w + b0.w, 0.f));
    o[4] = f2bf(fmaxf((b.x - m) * rsd * g1.x + b1.x, 0.f));
    o[5] = f2bf(fmaxf((b.y - m) * rsd * g1.y + b1.y, 0.f));
    o[6] = f2bf(fmaxf((b.z - m) * rsd * g1.z + b1.z, 0.f));
    o[7] = f2bf(fmaxf((b.w - m) * rsd * g1.w + b1.w, 0.f));
    *(short8*)&p.cat_bf[(size_t)r * (2 * CH) + g * 8] = o;
}

// ==================================================================== edge stats
// R13: computes group stats AND materializes the full normalized edge-MLP
// input e1n[E][768] = bf16(relu(gn_g24(cat(x[row], x[col], eattr)))) once.
__global__ __launch_bounds__(256) void estats_kernel(
    const float* __restrict__ eattr, const int* __restrict__ rowi,
    const int* __restrict__ coli, const float2* __restrict__ xs,
    const short* __restrict__ x_bf,
    const float* __restrict__ g1v, const float* __restrict__ b1v,
    short* __restrict__ e1n, int* __restrict__ counts, int E)
{
    __shared__ float2 ea[8][32];
    __shared__ float2 musr[8][32];
    int t = threadIdx.x;
    int slot = t >> 5, g = t & 31;
    int e = blockIdx.x * 8 + slot;
    float4 a = *(const float4*)&eattr[(size_t)e * CH + g * 8];
    float4 b = *(const float4*)&eattr[(size_t)e * CH + g * 8 + 4];
    float s  = a.x + a.y + a.z + a.w + b.x + b.y + b.z + b.w;
    float s2 = a.x*a.x + a.y*a.y + a.z*a.z + a.w*a.w
             + b.x*b.x + b.y*b.y + b.z*b.z + b.w*b.w;
    ea[slot][g] = make_float2(s, s2);
    int r = rowi[e], c = coli[e];
    if (g == 0) atomicAdd(&counts[c], 1);
    __syncthreads();
    float S = 0.f, S2 = 0.f;
    #pragma unroll
    for (int j = 0; j < 3; j++) {
        int b3 = 3 * g + j;
        int src = b3 >> 5, idx = b3 & 31;
        float2 v;
        if (src == 0)      v = xs[(size_t)r * 32 + idx];
        else if (src == 1) v = xs[(size_t)c * 32 + idx];
        else               v = ea[slot][idx];
        S += v.x; S2 += v.y;
    }
    float m = S * (1.f / 24.f);
    float var = S2 * (1.f / 24.f) - m * m;
    musr[slot][g] = make_float2(m, rsqrtf(var + 1e-5f));
    __syncthreads();
    // normalize all 3 segments; 8-chunks never cross a group of 24
    #pragma unroll
    for (int seg = 0; seg < 3; seg++) {
        int pos = seg * 256 + g * 8;
        float2 ms = musr[slot][pos / 24];
        float4 ga  = *(const float4*)&g1v[pos];
        float4 ga2 = *(const float4*)&g1v[pos + 4];
        float4 gb  = *(const float4*)&b1v[pos];
        float4 gb2 = *(const float4*)&b1v[pos + 4];
        float v0, v1, v2, v3, v4, v5, v6, v7;
        if (seg == 2) {
            v0 = a.x; v1 = a.y; v2 = a.z; v3 = a.w;
            v4 = b.x; v5 = b.y; v6 = b.z; v7 = b.w;
        } else {
            const short* srow = x_bf + (size_t)(seg == 0 ? r : c) * CH + g * 8;
            short8 v8 = *(const short8*)srow;
            v0 = bf2f(v8[0]); v1 = bf2f(v8[1]); v2 = bf2f(v8[2]); v3 = bf2f(v8[3]);
            v4 = bf2f(v8[4]); v5 = bf2f(v8[5]); v6 = bf2f(v8[6]); v7 = bf2f(v8[7]);
        }
        short8 o;
        o[0] = f2bf(fmaxf((v0 - ms.x) * ms.y * ga.x  + gb.x,  0.f));
        o[1] = f2bf(fmaxf((v1 - ms.x) * ms.y * ga.y  + gb.y,  0.f));
        o[2] = f2bf(fmaxf((v2 - ms.x) * ms.y * ga.z  + gb.z,  0.f));
        o[3] = f2bf(fmaxf((v3 - ms.x) * ms.y * ga.w  + gb.w,  0.f));
        o[4] = f2bf(fmaxf((v4 - ms.x) * ms.y * ga2.x + gb2.x, 0.f));
        o[5] = f2bf(fmaxf((v5 - ms.x) * ms.y * ga2.y + gb2.y, 0.f));
        o[6] = f2bf(fmaxf((v6 - ms.x) * ms.y * ga2.z + gb2.z, 0.f));
        o[7] = f2bf(fmaxf((v7 - ms.x) * ms.y * ga2.w + gb2.w, 0.f));
        *(short8*)&e1n[(size_t)e * 768 + pos] = o;
    }
}

// ==================================================================== attention
// block = node; fused scoring (all 4 waves cooperate) + per-wave (=head)
// online softmax + PV. Scores never touch global memory.
__global__ __launch_bounds__(256) void attn_kernel(
    const short* __restrict__ qb, const short* __restrict__ kvb,
    const int* __restrict__ offsets, const int* __restrict__ elist,
    const float* __restrict__ vbar, short* __restrict__ g_bf, int N, int E)
{
    __shared__ int eidx[64];
    __shared__ float scl[4 * 64];
    int n = blockIdx.x;
    int wave = threadIdx.x >> 6;
    int lane = threadIdx.x & 63;
    int s0 = offsets[n], s1 = offsets[n + 1];
    float q0 = bf2f(qb[(size_t)n * CH + lane]);
    float q1 = bf2f(qb[(size_t)n * CH + 64 + lane]);
    float q2 = bf2f(qb[(size_t)n * CH + 128 + lane]);
    float q3 = bf2f(qb[(size_t)n * CH + 192 + lane]);
    float out = 0.f, m = -INFINITY, l = 0.f;
    for (int base = s0; base < s1; base += 64) {
        int cn = s1 - base; if (cn > 64) cn = 64;
        if (wave == 0 && lane < cn) eidx[lane] = elist[base + lane];
        __syncthreads();
        for (int j = wave; j < cn; j += 4) {
            int e = eidx[j];
            const short* kr = kvb + (size_t)e * 512;
            float d0 = warp_sum64(q0 * bf2f(kr[lane]));
            float d1 = warp_sum64(q1 * bf2f(kr[64 + lane]));
            float d2 = warp_sum64(q2 * bf2f(kr[128 + lane]));
            float d3 = warp_sum64(q3 * bf2f(kr[192 + lane]));
            if (lane == 0) {
                scl[j]       = d0 * 0.125f;   // 1/sqrt(64)
                scl[64 + j]  = d1 * 0.125f;
                scl[128 + j] = d2 * 0.125f;
                scl[192 + j] = d3 * 0.125f;
            }
        }
        __syncthreads();
        float s = (lane < cn) ? scl[wave * 64 + lane] : -INFINITY;
        float mc = warp_max64(s);
        float nm = fmaxf(m, mc);
        float scale = __expf(m - nm);
        float pp = (lane < cn) ? __expf(s - nm) : 0.f;
        float ps = warp_sum64(pp);
        l = l * scale + ps;
        out *= scale;
        m = nm;
        for (int i = 0; i < cn; i++) {
            float pi = __shfl(pp, i, 64);
            int ei = eidx[i];
            out += pi * bf2f(kvb[(size_t)ei * 512 + 256 + wave * 64 + lane]);
        }
        __syncthreads();   // protect eidx/scl before next chunk
    }
    float res;
    if (s1 > s0) res = out / l;
    else         res = vbar[wave * 64 + lane] * (1.f / (float)E);  // uniform over all E
    g_bf[(size_t)n * CH + wave * 64 + lane] = f2bf(res);
}

// ==================================================================== launch
extern "C" void kernel_launch(void* const* d_in, const int* in_sizes, int n_in,
                              void* d_out, int out_size, void* d_ws, size_t ws_size,
                              hipStream_t stream)
{
    const float* x       = (const float*)d_in[0];
    const int*   ei      = (const int*)d_in[1];
    const float* eattr   = (const float*)d_in[2];
    const float* gn_e1_g = (const float*)d_in[3];
    const float* gn_e1_b = (const float*)d_in[4];
    const float* We1     = (const float*)d_in[5];
    const float* be1     = (const float*)d_in[6];
    const float* gn_e2_g = (const float*)d_in[7];
    const float* gn_e2_b = (const float*)d_in[8];
    const float* We2     = (const float*)d_in[9];
    const float* be2     = (const float*)d_in[10];
    const float* gn_n_g  = (const float*)d_in[11];
    const float* gn_n_b  = (const float*)d_in[12];
    const float* Wq      = (const float*)d_in[13];
    const float* bq      = (const float*)d_in[14];
    const float* Wk      = (const float*)d_in[15];
    const float* bk      = (const float*)d_in[16];
    const float* Wv      = (const float*)d_in[17];
    const float* bv      = (const float*)d_in[18];
    const float* Wo      = (const float*)d_in[19];
    const float* bo      = (const float*)d_in[20];
    const float* Wn1     = (const float*)d_in[21];
    const float* bn1     = (const float*)d_in[22];
    const float* gn_n2_g = (const float*)d_in[23];
    const float* gn_n2_b = (const float*)d_in[24];
    const float* Wn2     = (const float*)d_in[25];
    const float* bn2     = (const float*)d_in[26];

    const int N = in_sizes[0] / CH;
    const int E = in_sizes[2] / CH;

    float* nout = (float*)d_out;
    float* eout = (float*)d_out + (size_t)N * CH;

    // ---- workspace ----
    char* base = (char*)d_ws;
    short* kv_bf  = (short*)base; base += (size_t)E * 512 * 2;
    short* h2_bf  = (short*)base; base += (size_t)E * CH * 2;
    short* eo_bf  = (short*)base; base += (size_t)E * CH * 2;
    short* e1n    = (short*)base; base += (size_t)E * 768 * 2;
    short* q_bf   = (short*)base; base += (size_t)N * CH * 2;
    short* g_bf   = (short*)base; base += (size_t)N * CH * 2;
    short* cat_bf = (short*)base; base += (size_t)N * 2 * CH * 2;
    short* hn_bf  = (short*)base; base += (size_t)N * CH * 2;
    short* x_bf   = (short*)base; base += (size_t)N * CH * 2;
    float2* xs    = (float2*)base; base += (size_t)N * 32 * 8;
    float* vbar   = (float*)base; base += 1024;
    float* bkv    = (float*)base; base += 2048;
    short* We1t = (short*)base; base += (size_t)768 * 256 * 2;
    short* We2t = (short*)base; base += (size_t)256 * 256 * 2;
    short* Wqt  = (short*)base; base += (size_t)256 * 256 * 2;
    short* Wkvt = (short*)base; base += (size_t)512 * 256 * 2;
    short* Wot  = (short*)base; base += (size_t)256 * 256 * 2;
    short* Wn1t = (short*)base; base += (size_t)512 * 256 * 2;
    short* Wn2t = (short*)base; base += (size_t)256 * 256 * 2;
    int* counts  = (int*)base;
    int* offsets = counts + N;
    int* cursor  = offsets + (N + 1) + 3;
    int* elist   = cursor + N;
    int* done    = elist + E;
    int* ticket  = done + 256;

    const int* rowi = ei;
    const int* coli = ei + E;

    dim3 blk(256);

    // ---- merged prep ----
    PrepPack pp;
    const float* wsrc[8] = {We1, We2, Wq, Wk, Wv, Wo, Wn1, Wn2};
    short* wdst[8] = {We1t, We2t, Wqt, Wkvt, Wkvt + (size_t)256 * 256, Wot, Wn1t, Wn2t};
    const int wKd[8] = {768, 256, 256, 256, 256, 256, 512, 256};
    int acc = 0;
    for (int i = 0; i < 8; i++) {
        pp.wsrc[i] = wsrc[i]; pp.wdst[i] = wdst[i]; pp.wK[i] = wKd[i];
        pp.wstart[i] = acc; acc += wKd[i] / 16;
    }
    pp.NW = acc;
    pp.NP = (N + 7) / 8;
    pp.x = x; pp.x_bf = x_bf; pp.cat_bf = cat_bf; pp.xs = xs;
    pp.gng = gn_n_g; pp.gnb = gn_n_b;
    pp.vbar = vbar; pp.bk = bk; pp.bv = bv; pp.bkv = bkv;
    pp.counts = counts; pp.N = N;
    pp.doneZ = done; pp.ticketZ = ticket;
    int nzero = (N + 255) / 256;
    prep_kernel<<<pp.NW + pp.NP + nzero, blk, 0, stream>>>(pp);

    estats_kernel<<<E / 8, blk, 0, stream>>>(eattr, rowi, coli, xs, x_bf,
                                             gn_e1_g, gn_e1_b, e1n, counts, E);

    GArgs ga = {};
    // ---- GEMM1: e1n GEMM (K=768) + Q GEMM (DUAL, K2=256) + scan row ----
    ga.A = e1n; ga.Bt = We1t; ga.bias = be1; ga.Cbf = h2_bf;
    ga.gamma = gn_e2_g; ga.beta = gn_e2_b;
    ga.M = E; ga.K = 3 * CH; ga.Nc = CH; ga.ldc = CH; ga.coff = 0;
    ga.A2 = x_bf; ga.Bt2 = Wqt; ga.bias2 = bq; ga.Cbf2 = q_bf;
    ga.M2 = N; ga.Nc2 = CH; ga.y_split = 256; ga.K2 = CH;
    ga.counts = counts; ga.offsets = offsets; ga.cursor = cursor; ga.Nn = N;
    mfma_gemm<64, 64, 1, 1, 0, 0, 1, 0, 1>
        <<<dim3(4, 256 + (N + 63) / 64 + 1), blk, 0, stream>>>(ga);

    // ---- chained GEMM2+GEMM3: one launch, ticket roles, spin gate ----
    ChainArgs ca;
    ca.A1 = h2_bf; ca.Bt1 = We2t; ca.bias1 = be2; ca.res1 = eattr;
    ca.C1 = eout; ca.Cbf1 = eo_bf;
    ca.A2 = eo_bf; ca.Bt2 = Wkvt; ca.bias2 = bkv; ca.Cbf2 = kv_bf;
    ca.vbar = vbar;
    ca.coli = coli; ca.cursor = cursor; ca.elist = elist;
    ca.M = E;
    ca.ticket = ticket; ca.done = done;
    chain_gemm<<<2048, blk, 0, stream>>>(ca);

    // ---- attention (scores fused in) ----
    attn_kernel<<<N, blk, 0, stream>>>(q_bf, kv_bf, offsets, elist, vbar, g_bf, N, E);

    // ---- Wo -> cat right half (bf16) ----
    ga = {};
    ga.A = g_bf; ga.Bt = Wot; ga.bias = bo; ga.Cbf = cat_bf;
    ga.M = N; ga.K = CH; ga.Nc = CH; ga.ldc = 2 * CH; ga.coff = CH;
    mfma_gemm<32, 64, 0, 0, 0, 0><<<dim3(4, (N + 31) / 32), blk, 0, stream>>>(ga);

    // ---- node MLP ----
    ga = {};
    ga.A = cat_bf; ga.Bt = Wn1t; ga.bias = bn1; ga.Cbf = hn_bf;
    ga.gamma = gn_n2_g; ga.beta = gn_n2_b;
    ga.M = N; ga.K = 2 * CH; ga.Nc = CH; ga.ldc = CH; ga.coff = 0;
    mfma_gemm<32, 64, 1, 0, 0, 0><<<dim3(4, (N + 31) / 32), blk, 0, stream>>>(ga);

    ga = {};
    ga.A = hn_bf; ga.Bt = Wn2t; ga.bias = bn2; ga.res = x; ga.C = nout;
    ga.M = N; ga.K = CH; ga.Nc = CH; ga.ldc = CH; ga.coff = 0;
    mfma_gemm<32, 64, 0, 0, 0, 0><<<dim3(4, (N + 31) / 32), blk, 0, stream>>>(ga);
}

// Round 13
// 226.031 us; speedup vs baseline: 1.8810x; 1.8810x over previous
//
#include <hip/hip_runtime.h>
#include <hip/hip_bf16.h>
#include <stdint.h>
#include <math.h>

#define CH 256

typedef __attribute__((ext_vector_type(8)))  short short8;
typedef __attribute__((ext_vector_type(16))) short short16;
typedef __attribute__((ext_vector_type(4)))  float f32x4;

#define GL2LDS16(g, l) __builtin_amdgcn_global_load_lds(                       \
    (const __attribute__((address_space(1))) void*)(g),                        \
    (__attribute__((address_space(3))) void*)(l), 16, 0, 0)

__device__ inline short f2bf(float f) {
    __hip_bfloat16 h = __float2bfloat16(f);
    short s;
    __builtin_memcpy(&s, &h, 2);
    return s;
}

__device__ inline float bf2f(short s) {
    unsigned u = ((unsigned)(unsigned short)s) << 16;
    float f;
    __builtin_memcpy(&f, &u, 4);
    return f;
}

__device__ inline float warp_sum64(float v) {
    v += __shfl_xor(v, 32, 64);
    v += __shfl_xor(v, 16, 64);
    v += __shfl_xor(v, 8, 64);
    v += __shfl_xor(v, 4, 64);
    v += __shfl_xor(v, 2, 64);
    v += __shfl_xor(v, 1, 64);
    return v;
}

__device__ inline float warp_max64(float v) {
    v = fmaxf(v, __shfl_xor(v, 32, 64));
    v = fmaxf(v, __shfl_xor(v, 16, 64));
    v = fmaxf(v, __shfl_xor(v, 8, 64));
    v = fmaxf(v, __shfl_xor(v, 4, 64));
    v = fmaxf(v, __shfl_xor(v, 2, 64));
    v = fmaxf(v, __shfl_xor(v, 1, 64));
    return v;
}

// ==================================================================== MFMA GEMM
// BMxBN tile, BK=64, 2x2 wave grid, 16x16x32 bf16 MFMA. Single-buffer
// 2-barrier K-loop. FINAL (R19 config, 225.5us):
//  - e1n materialized once in estats (R13)
//  - XCD-aware swizzle on all E-row GEMMs (R14)
//  - CSR scan folded into GEMM1 grid (R11); KV 2-panel (R11)
//  - Q GEMM rides GEMM1's DUAL role (R19) — no GEMM3 tail wave
// Measured dead ends: BN=128 (R9), per-block tail fusion (R10), explicit
// dbuf (R12), grid.sync cooperative tail (R15, ~50us/barrier), Wo-fold
// (R16-18, fuse cost > fold win), ticket+spin producer-consumer merge
// (R20, 284us — spinning consumers starve producers). On this 8-XCD chip,
// cross-block waits cost more than the launch boundaries they replace.
struct GArgs {
    const short* A; const short* Bt; const float* bias; const float* res;
    float* C; short* Cbf;
    const float* gamma; const float* beta; float* vbar;
    int M, K, Nc, ldc, coff;
    const short* A2; const short* Bt2; const float* bias2; short* Cbf2;
    int M2, Nc2, y_split, K2;
    const int* coli;
    int* cursor; int* elist;
    const int* counts; int* offsets; int Nn;   // SCAN role
};

template <int BM, int BN, int EPI, int DUAL, int VB, int FILL,
          int SCAN = 0, int PAN2 = 0, int XSWZ = 0>
__global__ __launch_bounds__(256) void mfma_gemm(GArgs g)
{
    constexpr int BK = 64;
    constexpr int HM = BM / 2, HN = BN / 2;
    constexpr int FM = HM / 16, FN = HN / 16;
    constexpr int PA = BM / 32;
    constexpr int PB = BN / 32;
    constexpr int NP2 = PAN2 ? 2 : 1;
    __shared__ short As[BM * BK];
    __shared__ short Bs[NP2 * BN * BK];

    const short* A = g.A; const short* Bt = g.Bt;
    const float* bias = g.bias; const float* res = g.res;
    float* C = g.C; short* Cbf = g.Cbf;
    int M = g.M, ldc = g.ldc, co = g.coff;
    int K = g.K;
    int by = blockIdx.y, bx = blockIdx.x;

    if constexpr (SCAN) {
        if (by == (int)gridDim.y - 1) {
            const int t0 = threadIdx.x;
            if (bx == 0) {
                int* ss = (int*)As;
                int base8 = t0 * 8;
                int loc[8]; int srun = 0;
                #pragma unroll
                for (int j = 0; j < 8; j++) {
                    int idx = base8 + j;
                    int c = (idx < g.Nn) ? g.counts[idx] : 0;
                    loc[j] = srun; srun += c;
                }
                ss[t0] = srun;
                __syncthreads();
                for (int off = 1; off < 256; off <<= 1) {
                    int v = (t0 >= off) ? ss[t0 - off] : 0;
                    __syncthreads();
                    ss[t0] += v;
                    __syncthreads();
                }
                int excl = (t0 > 0) ? ss[t0 - 1] : 0;
                #pragma unroll
                for (int j = 0; j < 8; j++) {
                    int idx = base8 + j;
                    if (idx < g.Nn) {
                        int v = excl + loc[j];
                        g.offsets[idx] = v;
                        g.cursor[idx]  = v;
                    }
                }
                if (t0 == 255) g.offsets[g.Nn] = ss[255];
            }
            return;
        }
    }

    bool qrole = false;
    if constexpr (DUAL) {
        if (by >= g.y_split) {
            by -= g.y_split;
            if (bx * BN >= g.Nc2) return;
            qrole = true;
            A = g.A2; Bt = g.Bt2; bias = g.bias2; Cbf = g.Cbf2;
            C = nullptr; res = nullptr;
            M = g.M2; ldc = g.Nc2; co = 0; K = g.K2;
        }
    }

    if constexpr (XSWZ) {
        if (!qrole) {
            int h = by * 4 + bx;               // gridDim.x == 4
            int lby = (h >> 5) * 8 + (h & 7);  // same-XCD ids share lby
            if (lby * BM >= M) return;         // guard padded rows
            by = lby;
            bx = (h >> 3) & 3;
        }
    }

    const int t = threadIdx.x;
    const int wave = t >> 6, lane = t & 63;
    const int q = lane >> 4, l16 = lane & 15;
    const int row0 = by * BM;
    const int col0 = bx * BN;
    const int wm = wave & 1, wn = wave >> 1;

    if constexpr (FILL) {
        if (!qrole && bx == 0 && t < BM) {
            int rg = row0 + t;
            if (rg < M) {
                int c = g.coli[rg];
                int p = atomicAdd(&g.cursor[c], 1);
                g.elist[p] = rg;
            }
        }
    }

    f32x4 acc[NP2][FM][FN];
    #pragma unroll
    for (int p2 = 0; p2 < NP2; p2++)
        #pragma unroll
        for (int i = 0; i < FM; i++)
            #pragma unroll
            for (int j = 0; j < FN; j++) acc[p2][i][j] = (f32x4){0.f, 0.f, 0.f, 0.f};

    for (int k0 = 0; k0 < K; k0 += BK) {
        #pragma unroll
        for (int p = 0; p < PA; p++) {
            int chunk = p * 256 + t;
            int r = chunk >> 3;
            int cs = (((chunk & 7) ^ (r & 7)) * 8);   // XOR bank swizzle
            int gr = row0 + r; if (gr >= M) gr = M - 1;
            const short* gsrc = A + (size_t)gr * K + k0 + cs;
            short* ldst = &As[(p * 256 + wave * 64) * 8];
            GL2LDS16(gsrc, ldst);
        }
        #pragma unroll
        for (int p2 = 0; p2 < NP2; p2++) {
            if (!(PAN2 && p2 == 1 && qrole)) {
                #pragma unroll
                for (int p = 0; p < PB; p++) {
                    int chunk = p * 256 + t;
                    int r = chunk >> 3;
                    int cs = (((chunk & 7) ^ (r & 7)) * 8);
                    const short* gsrc = Bt + (size_t)(col0 + p2 * 256 + r) * K + k0 + cs;
                    short* ldst = &Bs[p2 * BN * BK + (p * 256 + wave * 64) * 8];
                    GL2LDS16(gsrc, ldst);
                }
            }
        }
        __syncthreads();
        #pragma unroll
        for (int ks = 0; ks < 2; ks++) {
            short8 af[FM];
            #pragma unroll
            for (int mi = 0; mi < FM; mi++) {
                int R = wm * HM + mi * 16 + l16;
                int slot = ((ks * 4 + q) ^ (R & 7)) * 8;
                af[mi] = *(const short8*)&As[R * BK + slot];
            }
            #pragma unroll
            for (int p2 = 0; p2 < NP2; p2++) {
                if (!(PAN2 && p2 == 1 && qrole)) {
                    short8 bfr[FN];
                    #pragma unroll
                    for (int ni = 0; ni < FN; ni++) {
                        int R = wn * HN + ni * 16 + l16;
                        int slot = ((ks * 4 + q) ^ (R & 7)) * 8;
                        bfr[ni] = *(const short8*)&Bs[p2 * BN * BK + R * BK + slot];
                    }
                    #pragma unroll
                    for (int mi = 0; mi < FM; mi++)
                        #pragma unroll
                        for (int ni = 0; ni < FN; ni++)
                            acc[p2][mi][ni] = __builtin_amdgcn_mfma_f32_16x16x32_bf16(
                                af[mi], bfr[ni], acc[p2][mi][ni], 0, 0, 0);
                }
            }
        }
        __syncthreads();
    }

    // ---- epilogue; C/D layout: col = l16, row = q*4 + r ----
    #pragma unroll
    for (int p2 = 0; p2 < NP2; p2++) {
        if (PAN2 && p2 == 1 && qrole) continue;
        #pragma unroll
        for (int ni = 0; ni < FN; ni++) {
            int cg = col0 + p2 * 256 + wn * HN + ni * 16 + l16;
            float bv = bias[cg];
            if (EPI == 1 && !qrole) {
                float ga = g.gamma[cg], be = g.beta[cg];
                #pragma unroll
                for (int mi = 0; mi < FM; mi++) {
                    #pragma unroll
                    for (int r = 0; r < 4; r++) {
                        float v = acc[p2][mi][ni][r] + bv;
                        float s = v, sq = v * v;
                        s += __shfl_xor(s, 1, 64);  sq += __shfl_xor(sq, 1, 64);
                        s += __shfl_xor(s, 2, 64);  sq += __shfl_xor(sq, 2, 64);
                        s += __shfl_xor(s, 4, 64);  sq += __shfl_xor(sq, 4, 64);
                        float mean = s * 0.125f;
                        float var = sq * 0.125f - mean * mean;
                        float o = fmaxf((v - mean) * rsqrtf(var + 1e-5f) * ga + be, 0.f);
                        int rg = row0 + wm * HM + mi * 16 + q * 4 + r;
                        if (rg < M) Cbf[(size_t)rg * ldc + co + cg] = f2bf(o);
                    }
                }
            } else {
                #pragma unroll
                for (int mi = 0; mi < FM; mi++) {
                    #pragma unroll
                    for (int r = 0; r < 4; r++) {
                        int rg = row0 + wm * HM + mi * 16 + q * 4 + r;
                        if (rg < M) {
                            float v = acc[p2][mi][ni][r] + bv;
                            if (res) v += res[(size_t)rg * ldc + co + cg];
                            if (C)   C[(size_t)rg * ldc + co + cg] = v;
                            if (Cbf) Cbf[(size_t)rg * ldc + co + cg] = f2bf(v);
                        }
                    }
                }
                if constexpr (VB) {
                    bool vpanel = PAN2 ? (p2 == 1) : (!qrole && cg >= 256);
                    if (vpanel && !qrole) {
                        float part = 0.f;
                        #pragma unroll
                        for (int mi = 0; mi < FM; mi++)
                            #pragma unroll
                            for (int r = 0; r < 4; r++) {
                                int rg = row0 + wm * HM + mi * 16 + q * 4 + r;
                                if (rg < M) part += acc[p2][mi][ni][r] + bv;
                            }
                        part += __shfl_xor(part, 16, 64);
                        part += __shfl_xor(part, 32, 64);
                        if (q == 0) atomicAdd(&g.vbar[cg - 256], part);
                    }
                }
            }
        }
    }
}

// ==================================================================== merged prep
struct PrepPack {
    const float* wsrc[8];
    short* wdst[8];
    int wK[8];
    int wstart[8];
    int NW, NP;
    const float* x;
    short* x_bf;
    short* cat_bf;
    float2* xs;
    const float* gng;
    const float* gnb;
    float* vbar;
    const float* bk;
    const float* bv;
    float* bkv;
    int* counts;
    int N;
};

__global__ __launch_bounds__(256) void prep_kernel(PrepPack p)
{
    int bid = blockIdx.x;
    int t = threadIdx.x;
    if (bid < p.NW) {
        int m = 0;
        #pragma unroll
        for (int i = 1; i < 8; i++) if (bid >= p.wstart[i]) m = i;
        int k0 = (bid - p.wstart[m]) * 16;
        const float* src = p.wsrc[m];
        short16 o;
        #pragma unroll
        for (int j = 0; j < 16; j++) o[j] = f2bf(src[(size_t)(k0 + j) * 256 + t]);
        *(short16*)(p.wdst[m] + (size_t)t * p.wK[m] + k0) = o;
        return;
    }
    if (bid >= p.NW + p.NP) {
        int i = (bid - p.NW - p.NP) * 256 + t;
        if (i < p.N) p.counts[i] = 0;
        return;
    }
    int pb = bid - p.NW;
    if (pb == 0) {
        p.vbar[t] = 0.f;
        p.bkv[t] = p.bk[t];
        p.bkv[256 + t] = p.bv[t];
    }
    int r = pb * 8 + (t >> 5);
    int g = t & 31;
    if (r >= p.N) return;
    size_t xb = (size_t)r * CH + g * 8;
    float4 a = *(const float4*)&p.x[xb];
    float4 b = *(const float4*)&p.x[xb + 4];
    short8 xr;
    xr[0] = f2bf(a.x); xr[1] = f2bf(a.y); xr[2] = f2bf(a.z); xr[3] = f2bf(a.w);
    xr[4] = f2bf(b.x); xr[5] = f2bf(b.y); xr[6] = f2bf(b.z); xr[7] = f2bf(b.w);
    *(short8*)&p.x_bf[xb] = xr;
    float s  = a.x + a.y + a.z + a.w + b.x + b.y + b.z + b.w;
    float s2 = a.x*a.x + a.y*a.y + a.z*a.z + a.w*a.w
             + b.x*b.x + b.y*b.y + b.z*b.z + b.w*b.w;
    p.xs[(size_t)r * 32 + g] = make_float2(s, s2);
    float m = s * 0.125f;
    float var = s2 * 0.125f - m * m;
    float rsd = rsqrtf(var + 1e-5f);
    float4 g0 = *(const float4*)&p.gng[g * 8];
    float4 g1 = *(const float4*)&p.gng[g * 8 + 4];
    float4 b0 = *(const float4*)&p.gnb[g * 8];
    float4 b1 = *(const float4*)&p.gnb[g * 8 + 4];
    short8 o;
    o[0] = f2bf(fmaxf((a.x - m) * rsd * g0.x + b0.x, 0.f));
    o[1] = f2bf(fmaxf((a.y - m) * rsd * g0.y + b0.y, 0.f));
    o[2] = f2bf(fmaxf((a.z - m) * rsd * g0.z + b0.z, 0.f));
    o[3] = f2bf(fmaxf((a.w - m) * rsd * g0.w + b0.w, 0.f));
    o[4] = f2bf(fmaxf((b.x - m) * rsd * g1.x + b1.x, 0.f));
    o[5] = f2bf(fmaxf((b.y - m) * rsd * g1.y + b1.y, 0.f));
    o[6] = f2bf(fmaxf((b.z - m) * rsd * g1.z + b1.z, 0.f));
    o[7] = f2bf(fmaxf((b.w - m) * rsd * g1.w + b1.w, 0.f));
    *(short8*)&p.cat_bf[(size_t)r * (2 * CH) + g * 8] = o;
}

// ==================================================================== edge stats
// R13: computes group stats AND materializes the full normalized edge-MLP
// input e1n[E][768] = bf16(relu(gn_g24(cat(x[row], x[col], eattr)))) once.
__global__ __launch_bounds__(256) void estats_kernel(
    const float* __restrict__ eattr, const int* __restrict__ rowi,
    const int* __restrict__ coli, const float2* __restrict__ xs,
    const short* __restrict__ x_bf,
    const float* __restrict__ g1v, const float* __restrict__ b1v,
    short* __restrict__ e1n, int* __restrict__ counts, int E)
{
    __shared__ float2 ea[8][32];
    __shared__ float2 musr[8][32];
    int t = threadIdx.x;
    int slot = t >> 5, g = t & 31;
    int e = blockIdx.x * 8 + slot;
    float4 a = *(const float4*)&eattr[(size_t)e * CH + g * 8];
    float4 b = *(const float4*)&eattr[(size_t)e * CH + g * 8 + 4];
    float s  = a.x + a.y + a.z + a.w + b.x + b.y + b.z + b.w;
    float s2 = a.x*a.x + a.y*a.y + a.z*a.z + a.w*a.w
             + b.x*b.x + b.y*b.y + b.z*b.z + b.w*b.w;
    ea[slot][g] = make_float2(s, s2);
    int r = rowi[e], c = coli[e];
    if (g == 0) atomicAdd(&counts[c], 1);
    __syncthreads();
    float S = 0.f, S2 = 0.f;
    #pragma unroll
    for (int j = 0; j < 3; j++) {
        int b3 = 3 * g + j;
        int src = b3 >> 5, idx = b3 & 31;
        float2 v;
        if (src == 0)      v = xs[(size_t)r * 32 + idx];
        else if (src == 1) v = xs[(size_t)c * 32 + idx];
        else               v = ea[slot][idx];
        S += v.x; S2 += v.y;
    }
    float m = S * (1.f / 24.f);
    float var = S2 * (1.f / 24.f) - m * m;
    musr[slot][g] = make_float2(m, rsqrtf(var + 1e-5f));
    __syncthreads();
    // normalize all 3 segments; 8-chunks never cross a group of 24
    #pragma unroll
    for (int seg = 0; seg < 3; seg++) {
        int pos = seg * 256 + g * 8;
        float2 ms = musr[slot][pos / 24];
        float4 ga  = *(const float4*)&g1v[pos];
        float4 ga2 = *(const float4*)&g1v[pos + 4];
        float4 gb  = *(const float4*)&b1v[pos];
        float4 gb2 = *(const float4*)&b1v[pos + 4];
        float v0, v1, v2, v3, v4, v5, v6, v7;
        if (seg == 2) {
            v0 = a.x; v1 = a.y; v2 = a.z; v3 = a.w;
            v4 = b.x; v5 = b.y; v6 = b.z; v7 = b.w;
        } else {
            const short* srow = x_bf + (size_t)(seg == 0 ? r : c) * CH + g * 8;
            short8 v8 = *(const short8*)srow;
            v0 = bf2f(v8[0]); v1 = bf2f(v8[1]); v2 = bf2f(v8[2]); v3 = bf2f(v8[3]);
            v4 = bf2f(v8[4]); v5 = bf2f(v8[5]); v6 = bf2f(v8[6]); v7 = bf2f(v8[7]);
        }
        short8 o;
        o[0] = f2bf(fmaxf((v0 - ms.x) * ms.y * ga.x  + gb.x,  0.f));
        o[1] = f2bf(fmaxf((v1 - ms.x) * ms.y * ga.y  + gb.y,  0.f));
        o[2] = f2bf(fmaxf((v2 - ms.x) * ms.y * ga.z  + gb.z,  0.f));
        o[3] = f2bf(fmaxf((v3 - ms.x) * ms.y * ga.w  + gb.w,  0.f));
        o[4] = f2bf(fmaxf((v4 - ms.x) * ms.y * ga2.x + gb2.x, 0.f));
        o[5] = f2bf(fmaxf((v5 - ms.x) * ms.y * ga2.y + gb2.y, 0.f));
        o[6] = f2bf(fmaxf((v6 - ms.x) * ms.y * ga2.z + gb2.z, 0.f));
        o[7] = f2bf(fmaxf((v7 - ms.x) * ms.y * ga2.w + gb2.w, 0.f));
        *(short8*)&e1n[(size_t)e * 768 + pos] = o;
    }
}

// ==================================================================== attention
// block = node; fused scoring (all 4 waves cooperate) + per-wave (=head)
// online softmax + PV. Scores never touch global memory.
__global__ __launch_bounds__(256) void attn_kernel(
    const short* __restrict__ qb, const short* __restrict__ kvb,
    const int* __restrict__ offsets, const int* __restrict__ elist,
    const float* __restrict__ vbar, short* __restrict__ g_bf, int N, int E)
{
    __shared__ int eidx[64];
    __shared__ float scl[4 * 64];
    int n = blockIdx.x;
    int wave = threadIdx.x >> 6;
    int lane = threadIdx.x & 63;
    int s0 = offsets[n], s1 = offsets[n + 1];
    float q0 = bf2f(qb[(size_t)n * CH + lane]);
    float q1 = bf2f(qb[(size_t)n * CH + 64 + lane]);
    float q2 = bf2f(qb[(size_t)n * CH + 128 + lane]);
    float q3 = bf2f(qb[(size_t)n * CH + 192 + lane]);
    float out = 0.f, m = -INFINITY, l = 0.f;
    for (int base = s0; base < s1; base += 64) {
        int cn = s1 - base; if (cn > 64) cn = 64;
        if (wave == 0 && lane < cn) eidx[lane] = elist[base + lane];
        __syncthreads();
        for (int j = wave; j < cn; j += 4) {
            int e = eidx[j];
            const short* kr = kvb + (size_t)e * 512;
            float d0 = warp_sum64(q0 * bf2f(kr[lane]));
            float d1 = warp_sum64(q1 * bf2f(kr[64 + lane]));
            float d2 = warp_sum64(q2 * bf2f(kr[128 + lane]));
            float d3 = warp_sum64(q3 * bf2f(kr[192 + lane]));
            if (lane == 0) {
                scl[j]       = d0 * 0.125f;   // 1/sqrt(64)
                scl[64 + j]  = d1 * 0.125f;
                scl[128 + j] = d2 * 0.125f;
                scl[192 + j] = d3 * 0.125f;
            }
        }
        __syncthreads();
        float s = (lane < cn) ? scl[wave * 64 + lane] : -INFINITY;
        float mc = warp_max64(s);
        float nm = fmaxf(m, mc);
        float scale = __expf(m - nm);
        float pp = (lane < cn) ? __expf(s - nm) : 0.f;
        float ps = warp_sum64(pp);
        l = l * scale + ps;
        out *= scale;
        m = nm;
        for (int i = 0; i < cn; i++) {
            float pi = __shfl(pp, i, 64);
            int ei = eidx[i];
            out += pi * bf2f(kvb[(size_t)ei * 512 + 256 + wave * 64 + lane]);
        }
        __syncthreads();   // protect eidx/scl before next chunk
    }
    float res;
    if (s1 > s0) res = out / l;
    else         res = vbar[wave * 64 + lane] * (1.f / (float)E);  // uniform over all E
    g_bf[(size_t)n * CH + wave * 64 + lane] = f2bf(res);
}

// ==================================================================== launch
extern "C" void kernel_launch(void* const* d_in, const int* in_sizes, int n_in,
                              void* d_out, int out_size, void* d_ws, size_t ws_size,
                              hipStream_t stream)
{
    const float* x       = (const float*)d_in[0];
    const int*   ei      = (const int*)d_in[1];
    const float* eattr   = (const float*)d_in[2];
    const float* gn_e1_g = (const float*)d_in[3];
    const float* gn_e1_b = (const float*)d_in[4];
    const float* We1     = (const float*)d_in[5];
    const float* be1     = (const float*)d_in[6];
    const float* gn_e2_g = (const float*)d_in[7];
    const float* gn_e2_b = (const float*)d_in[8];
    const float* We2     = (const float*)d_in[9];
    const float* be2     = (const float*)d_in[10];
    const float* gn_n_g  = (const float*)d_in[11];
    const float* gn_n_b  = (const float*)d_in[12];
    const float* Wq      = (const float*)d_in[13];
    const float* bq      = (const float*)d_in[14];
    const float* Wk      = (const float*)d_in[15];
    const float* bk      = (const float*)d_in[16];
    const float* Wv      = (const float*)d_in[17];
    const float* bv      = (const float*)d_in[18];
    const float* Wo      = (const float*)d_in[19];
    const float* bo      = (const float*)d_in[20];
    const float* Wn1     = (const float*)d_in[21];
    const float* bn1     = (const float*)d_in[22];
    const float* gn_n2_g = (const float*)d_in[23];
    const float* gn_n2_b = (const float*)d_in[24];
    const float* Wn2     = (const float*)d_in[25];
    const float* bn2     = (const float*)d_in[26];

    const int N = in_sizes[0] / CH;
    const int E = in_sizes[2] / CH;

    float* nout = (float*)d_out;
    float* eout = (float*)d_out + (size_t)N * CH;

    // ---- workspace ----
    char* base = (char*)d_ws;
    short* kv_bf  = (short*)base; base += (size_t)E * 512 * 2;
    short* h2_bf  = (short*)base; base += (size_t)E * CH * 2;
    short* eo_bf  = (short*)base; base += (size_t)E * CH * 2;
    short* e1n    = (short*)base; base += (size_t)E * 768 * 2;
    short* q_bf   = (short*)base; base += (size_t)N * CH * 2;
    short* g_bf   = (short*)base; base += (size_t)N * CH * 2;
    short* cat_bf = (short*)base; base += (size_t)N * 2 * CH * 2;
    short* hn_bf  = (short*)base; base += (size_t)N * CH * 2;
    short* x_bf   = (short*)base; base += (size_t)N * CH * 2;
    float2* xs    = (float2*)base; base += (size_t)N * 32 * 8;
    float* vbar   = (float*)base; base += 1024;
    float* bkv    = (float*)base; base += 2048;
    short* We1t = (short*)base; base += (size_t)768 * 256 * 2;
    short* We2t = (short*)base; base += (size_t)256 * 256 * 2;
    short* Wqt  = (short*)base; base += (size_t)256 * 256 * 2;
    short* Wkvt = (short*)base; base += (size_t)512 * 256 * 2;
    short* Wot  = (short*)base; base += (size_t)256 * 256 * 2;
    short* Wn1t = (short*)base; base += (size_t)512 * 256 * 2;
    short* Wn2t = (short*)base; base += (size_t)256 * 256 * 2;
    int* counts  = (int*)base;
    int* offsets = counts + N;
    int* cursor  = offsets + (N + 1) + 3;
    int* elist   = cursor + N;

    const int* rowi = ei;
    const int* coli = ei + E;

    dim3 blk(256);

    // ---- merged prep ----
    PrepPack pp;
    const float* wsrc[8] = {We1, We2, Wq, Wk, Wv, Wo, Wn1, Wn2};
    short* wdst[8] = {We1t, We2t, Wqt, Wkvt, Wkvt + (size_t)256 * 256, Wot, Wn1t, Wn2t};
    const int wKd[8] = {768, 256, 256, 256, 256, 256, 512, 256};
    int acc = 0;
    for (int i = 0; i < 8; i++) {
        pp.wsrc[i] = wsrc[i]; pp.wdst[i] = wdst[i]; pp.wK[i] = wKd[i];
        pp.wstart[i] = acc; acc += wKd[i] / 16;
    }
    pp.NW = acc;
    pp.NP = (N + 7) / 8;
    pp.x = x; pp.x_bf = x_bf; pp.cat_bf = cat_bf; pp.xs = xs;
    pp.gng = gn_n_g; pp.gnb = gn_n_b;
    pp.vbar = vbar; pp.bk = bk; pp.bv = bv; pp.bkv = bkv;
    pp.counts = counts; pp.N = N;
    int nzero = (N + 255) / 256;
    prep_kernel<<<pp.NW + pp.NP + nzero, blk, 0, stream>>>(pp);

    estats_kernel<<<E / 8, blk, 0, stream>>>(eattr, rowi, coli, xs, x_bf,
                                             gn_e1_g, gn_e1_b, e1n, counts, E);

    GArgs ga = {};
    // ---- GEMM1: e1n GEMM (K=768) + Q GEMM (DUAL, K2=256) + scan row ----
    ga.A = e1n; ga.Bt = We1t; ga.bias = be1; ga.Cbf = h2_bf;
    ga.gamma = gn_e2_g; ga.beta = gn_e2_b;
    ga.M = E; ga.K = 3 * CH; ga.Nc = CH; ga.ldc = CH; ga.coff = 0;
    ga.A2 = x_bf; ga.Bt2 = Wqt; ga.bias2 = bq; ga.Cbf2 = q_bf;
    ga.M2 = N; ga.Nc2 = CH; ga.y_split = 256; ga.K2 = CH;
    ga.counts = counts; ga.offsets = offsets; ga.cursor = cursor; ga.Nn = N;
    mfma_gemm<64, 64, 1, 1, 0, 0, 1, 0, 1>
        <<<dim3(4, 256 + (N + 63) / 64 + 1), blk, 0, stream>>>(ga);

    // ---- GEMM2: eout (f32, +eattr residual) + eo_bf, XCD swizzle ----
    ga = {};
    ga.A = h2_bf; ga.Bt = We2t; ga.bias = be2; ga.res = eattr;
    ga.C = eout; ga.Cbf = eo_bf;
    ga.M = E; ga.K = CH; ga.Nc = CH; ga.ldc = CH; ga.coff = 0;
    mfma_gemm<64, 64, 0, 0, 0, 0, 0, 0, 1><<<dim3(4, 256), blk, 0, stream>>>(ga);

    // ---- GEMM3: pure KV (2-panel, vbar, CSR fill, XCD swizzle), no tail ----
    ga = {};
    ga.A = eo_bf; ga.Bt = Wkvt; ga.bias = bkv; ga.Cbf = kv_bf; ga.vbar = vbar;
    ga.M = E; ga.K = CH; ga.Nc = 512; ga.ldc = 512; ga.coff = 0;
    ga.coli = coli; ga.cursor = cursor; ga.elist = elist;
    mfma_gemm<64, 64, 0, 0, 1, 1, 0, 1, 1><<<dim3(4, 256), blk, 0, stream>>>(ga);

    // ---- attention (scores fused in) ----
    attn_kernel<<<N, blk, 0, stream>>>(q_bf, kv_bf, offsets, elist, vbar, g_bf, N, E);

    // ---- Wo -> cat right half (bf16) ----
    ga = {};
    ga.A = g_bf; ga.Bt = Wot; ga.bias = bo; ga.Cbf = cat_bf;
    ga.M = N; ga.K = CH; ga.Nc = CH; ga.ldc = 2 * CH; ga.coff = CH;
    mfma_gemm<32, 64, 0, 0, 0, 0><<<dim3(4, (N + 31) / 32), blk, 0, stream>>>(ga);

    // ---- node MLP ----
    ga = {};
    ga.A = cat_bf; ga.Bt = Wn1t; ga.bias = bn1; ga.Cbf = hn_bf;
    ga.gamma = gn_n2_g; ga.beta = gn_n2_b;
    ga.M = N; ga.K = 2 * CH; ga.Nc = CH; ga.ldc = CH; ga.coff = 0;
    mfma_gemm<32, 64, 1, 0, 0, 0><<<dim3(4, (N + 31) / 32), blk, 0, stream>>>(ga);

    ga = {};
    ga.A = hn_bf; ga.Bt = Wn2t; ga.bias = bn2; ga.res = x; ga.C = nout;
    ga.M = N; ga.K = CH; ga.Nc = CH; ga.ldc = CH; ga.coff = 0;
    mfma_gemm<32, 64, 0, 0, 0, 0><<<dim3(4, (N + 31) / 32), blk, 0, stream>>>(ga);
}